// Round 1
// baseline (1526.090 us; speedup 1.0000x reference)
//
#include <hip/hip_runtime.h>
#include <math.h>

typedef unsigned long long u64;
typedef unsigned int u32;

#define BF 8
#define NPTS 16384
#define M_SN 1024
#define CCH 64
#define KNN 16
#define NTHR1 1024
#define KPER 16            // NPTS / NTHR1
#define TBL 4096
#define CCAP 3072
#define REM 1008           // M - 16 gripper slots

// output layout (flat float32, concatenated in return order)
constexpr size_t O0 = 0;                 // neighbor_feats 8*1024*16*64
constexpr size_t O1 = 8388608;           // supernode_xyz 8*1024*3
constexpr size_t O2 = 8413184;           // neighbor_mask 8*1024*16
constexpr size_t O3 = 8544256;           // out_idx 8*1024
constexpr size_t O4 = 8552448;           // out_valid 8*1024
constexpr size_t O5 = 8560640;           // out_bucket 8*1024

__device__ __forceinline__ bool is_valid_el(const void* vp, int mode, long long i) {
  if (mode == 1) return ((const unsigned char*)vp)[i] != 0;
  if (mode == 2) return ((const float*)vp)[i] != 0.0f;
  return ((const int*)vp)[i] != 0;
}

// monotone-decreasing encode: larger float -> smaller u32 (NaN sorts first; -inf last)
__device__ __forceinline__ u32 desc_enc(float f) {
  u32 u = __float_as_uint(f);
  u32 s = (u & 0x80000000u) ? ~u : (u | 0x80000000u);
  return ~s;
}
__device__ __forceinline__ bool enc_finite(u32 d) {
  u32 s = ~d;
  u32 u = (s & 0x80000000u) ? (s & 0x7FFFFFFFu) : ~s;
  return (u & 0x7F800000u) != 0x7F800000u;
}

__device__ __forceinline__ u64 block_min_u64(u64 v, u64* red, int t) {
  red[t] = v;
  __syncthreads();
  for (int s = NTHR1 / 2; s > 0; s >>= 1) {
    if (t < s) { u64 o = red[t + s]; if (o < red[t]) red[t] = o; }
    __syncthreads();
  }
  u64 r = red[0];
  __syncthreads();
  return r;
}

// ---------------- K0: detect how `valid` (bool) is stored ----------------
__global__ void detect_valid(const unsigned* __restrict__ w, int nwords, int* __restrict__ flag) {
  __shared__ int cls;
  int t = threadIdx.x;
  if (t == 0) cls = 0;
  __syncthreads();
  int local = 0;
  for (int i = t; i < nwords; i += blockDim.x) {
    unsigned v = w[i];
    if (v == 0x3F800000u) local = 2;            // float32 storage
    else if (v != 0u && v != 1u) local = max(local, 1); // packed bytes
  }
  if (local) atomicMax(&cls, local);
  __syncthreads();
  if (t == 0) flag[0] = cls;                    // 0=int32, 1=uint8, 2=float32
}

// ---------------- K1: supernode sampling (one block per batch row) ----------------
__global__ __launch_bounds__(1024)
void sample_kernel(const float* __restrict__ xyz, const void* __restrict__ validp,
                   const float* __restrict__ state, const int* __restrict__ mask_id,
                   const float* __restrict__ extra, const float* __restrict__ glob,
                   const int* __restrict__ flagp, float* __restrict__ out) {
  __shared__ u64 red[NTHR1];        // 8 KB
  __shared__ int table[TBL];        // 16 KB (mask min-index table, reused as histogram)
  __shared__ int scanb[NTHR1];      // 4 KB
  __shared__ int mpick[REM];        // ~4 KB
  __shared__ u64 cand[CCAP];        // 24 KB
  __shared__ int gsorted[REM];      // ~4 KB
  __shared__ int head_i[16];
  __shared__ int head_bk[16];
  __shared__ int sh[8];             // 0:rhv 1:first_valid 2:has_radius 3:nmask_total 4:n_avail 5:cand_cnt 6:B

  const int b = blockIdx.x, t = threadIdx.x;
  const int vmode = flagp[0];
  const float* xyzb = xyz + (size_t)b * NPTS * 3;
  const int* midb = mask_id + (size_t)b * NPTS;
  const float* exb = extra + (size_t)b * NPTS;
  const float* glb = glob + (size_t)b * NPTS;

  if (t < 8) sh[t] = 0;
  if (t == 1) sh[1] = 0x7FFFFFFF;
  if (t == 6) sh[6] = 0x7FFFFFFF;
  __syncthreads();

  // ---- validity bits (element i = k*1024 + t) ----
  u32 vbits = 0;
#pragma unroll
  for (int k = 0; k < KPER; k++) {
    int i = k * NTHR1 + t;
    if (is_valid_el(validp, vmode, (long long)b * NPTS + i)) vbits |= 1u << k;
  }
  if (vbits) {
    atomicOr(&sh[0], 1);
    atomicMin(&sh[1], (__ffs(vbits) - 1) * NTHR1 + t);
  }

  // ---- gripper distances ----
  float gx = state[b * 8 + 0], gy = state[b * 8 + 1], gz = state[b * 8 + 2];
  float gd[KPER];
  u32 inr = 0;
#pragma unroll
  for (int k = 0; k < KPER; k++) {
    int i = k * NTHR1 + t;
    float dx = xyzb[3 * i] - gx, dy = xyzb[3 * i + 1] - gy, dz = xyzb[3 * i + 2] - gz;
    float d = sqrtf((dx * dx + dy * dy) + dz * dz);
    gd[k] = d;
    if (((vbits >> k) & 1u) && d <= 0.1f) inr |= 1u << k;
  }
  if (inr) atomicOr(&sh[2], 1);
  __syncthreads();

  const int rhv = sh[0];
  const int first_valid = rhv ? sh[1] : 0;
  const u32 elig = vbits & (sh[2] ? inr : 0xFFFFu);
  u32 sel = 0;

  // ---- 16 gripper picks: iterative argmin of (gdist, idx) over eligible ----
  for (int it = 0; it < 16; ++it) {
    u64 best = ~0ull;
#pragma unroll
    for (int k = 0; k < KPER; k++) {
      if (((elig >> k) & 1u) && !((sel >> k) & 1u)) {
        u64 key = ((u64)__float_as_uint(gd[k]) << 32) | (u32)(k * NTHR1 + t);
        if (key < best) best = key;
      }
    }
    u64 w = block_min_u64(best, red, t);
    bool keep = (w >> 32) < 0x7F800000ull;   // finite distance found
    int idx = (int)(w & 0xFFFFFFFFu);
    if (t == 0) { head_i[it] = keep ? idx : first_valid; head_bk[it] = keep ? 1 : -1; }
    if (keep && (idx & (NTHR1 - 1)) == t) sel |= 1u << (idx >> 10);
  }

  // ---- mask stage: min index per distinct mask_id among candidates ----
  for (int j = t; j < TBL; j += NTHR1) table[j] = 0x7FFFFFFF;
  __syncthreads();
#pragma unroll
  for (int k = 0; k < KPER; k++) {
    if (((vbits >> k) & 1u) && !((sel >> k) & 1u)) {
      int i = k * NTHR1 + t;
      int id = midb[i];
      if ((u32)id < TBL) atomicMin(&table[id], i);
    }
  }
  __syncthreads();
  int cnt = 0;
#pragma unroll
  for (int q = 0; q < 4; q++) cnt += (table[4 * t + q] != 0x7FFFFFFF);
  scanb[t] = cnt;
  __syncthreads();
  for (int off = 1; off < NTHR1; off <<= 1) {
    int v = (t >= off) ? scanb[t - off] : 0;
    __syncthreads();
    scanb[t] += v;
    __syncthreads();
  }
  {
    int excl = scanb[t] - cnt;
    if (t == NTHR1 - 1) sh[3] = scanb[t];
    int pos = excl;
#pragma unroll
    for (int q = 0; q < 4; q++) {
      int v = table[4 * t + q];
      if (v != 0x7FFFFFFF) { if (pos < REM) mpick[pos] = v; pos++; }
    }
  }
  __syncthreads();
  const int nm = min(sh[3], REM);
  for (int j = 0; j < nm; j++) {
    int p = mpick[j];
    if ((p & (NTHR1 - 1)) == t) sel |= 1u << (p >> 10);
  }

  // ---- extra stage (only active when < 8 distinct mask ids) ----
  u32 extra_used = 0;
  if (nm < 8 && rhv) {
    u32 extrbits = 0;
    for (int j = 0; j < 8; j++) {
      u64 best = ~0ull;
#pragma unroll
      for (int k = 0; k < KPER; k++) {
        if (((vbits >> k) & 1u) && !((sel >> k) & 1u) && !((extrbits >> k) & 1u)) {
          int i = k * NTHR1 + t;
          u64 key = ((u64)desc_enc(exb[i]) << 32) | (u32)i;
          if (key < best) best = key;
        }
      }
      u64 w = block_min_u64(best, red, t);
      if (w == ~0ull) break;                  // uniform: no candidates left
      int idx = (int)(w & 0xFFFFFFFFu);
      bool fin = enc_finite((u32)(w >> 32));
      if ((idx & (NTHR1 - 1)) == t) extrbits |= 1u << (idx >> 10);
      if (j >= nm && fin) {
        extra_used |= 1u << j;
        if (t == 0) mpick[j] = idx;
        if ((idx & (NTHR1 - 1)) == t) sel |= 1u << (idx >> 10);
      }
    }
    __syncthreads();
  }

  // ---- global stage: exact ordered top-1008 of (global_score desc, idx asc) ----
  for (int j = t; j < TBL; j += NTHR1) table[j] = 0;
  for (int j = t; j < REM; j += NTHR1) gsorted[j] = -1;
  __syncthreads();
  u32 cbits = vbits & ~sel;
  atomicAdd(&sh[4], __popc(cbits));
  u32 dk[KPER];
#pragma unroll
  for (int k = 0; k < KPER; k++) {
    if ((cbits >> k) & 1u) {
      dk[k] = desc_enc(glb[k * NTHR1 + t]);
      atomicAdd(&table[dk[k] >> 20], 1);
    }
  }
  __syncthreads();
  const int nav = sh[4];
  const int T = min(REM, nav);
  if (T > 0) {
    int c4 = table[4 * t] + table[4 * t + 1] + table[4 * t + 2] + table[4 * t + 3];
    scanb[t] = c4;
    __syncthreads();
    for (int off = 1; off < NTHR1; off <<= 1) {
      int v = (t >= off) ? scanb[t - off] : 0;
      __syncthreads();
      scanb[t] += v;
      __syncthreads();
    }
    int cum = scanb[t] - c4;
#pragma unroll
    for (int q = 0; q < 4; q++) {
      int prev = cum;
      cum += table[4 * t + q];
      if (prev < T && cum >= T) atomicMin(&sh[6], 4 * t + q);
    }
    __syncthreads();
    const int B = sh[6];
#pragma unroll
    for (int k = 0; k < KPER; k++) {
      if (((cbits >> k) & 1u) && (int)(dk[k] >> 20) <= B) {
        int pos = atomicAdd(&sh[5], 1);
        if (pos < CCAP) cand[pos] = ((u64)dk[k] << 32) | (u32)(k * NTHR1 + t);
      }
    }
    __syncthreads();
    int nc = min(sh[5], CCAP);
    if (sh[5] <= CCAP) {
      // exact rank by counting (keys unique: idx is in low bits)
      for (int c = t; c < nc; c += NTHR1) {
        u64 key = cand[c];
        int r = 0;
        for (int j = 0; j < nc; j++) r += (cand[j] < key);
        if (r < REM) {
          int ix = (int)(key & 0xFFFFFFFFu);
          gsorted[r] = enc_finite((u32)(key >> 32)) ? ix : (ix | (int)0x80000000);
        }
      }
    } else {
      // pathological-ties fallback: iterative extraction (never triggers on bench data)
      u32 gext = 0;
      for (int j = 0; j < T; j++) {
        u64 best = ~0ull;
#pragma unroll
        for (int k = 0; k < KPER; k++) {
          if (((cbits >> k) & 1u) && !((gext >> k) & 1u)) {
            u64 key = ((u64)dk[k] << 32) | (u32)(k * NTHR1 + t);
            if (key < best) best = key;
          }
        }
        u64 w = block_min_u64(best, red, t);
        if (w == ~0ull) break;
        int idx = (int)(w & 0xFFFFFFFFu);
        if ((idx & (NTHR1 - 1)) == t) gext |= 1u << (idx >> 10);
        if (t == 0) gsorted[j] = enc_finite((u32)(w >> 32)) ? idx : (idx | (int)0x80000000);
      }
    }
    __syncthreads();
  }

  // ---- emit out_idx / out_valid / out_bucket / supernode_xyz ----
  {
    int slot = t;
    int idx, bucket;
    if (slot < 16) {
      idx = head_i[slot];
      bucket = head_bk[slot];
    } else {
      int jj = slot - 16;
      bool mk = (jj < nm) || (jj < 8 && ((extra_used >> jj) & 1u));
      if (mk) { idx = mpick[jj]; bucket = 2; }
      else {
        int g = gsorted[jj];
        if (rhv && g >= 0) { idx = g; bucket = 0; }
        else { idx = first_valid; bucket = -1; }
      }
    }
    bool ov = rhv && is_valid_el(validp, vmode, (long long)b * NPTS + idx);
    int ob = ov ? bucket : -1;
    size_t o = (size_t)b * M_SN + slot;
    out[O3 + o] = (float)idx;
    out[O4 + o] = ov ? 1.0f : 0.0f;
    out[O5 + o] = (float)ob;
    out[O1 + 3 * o + 0] = xyzb[3 * idx + 0];
    out[O1 + 3 * o + 1] = xyzb[3 * idx + 1];
    out[O1 + 3 * o + 2] = xyzb[3 * idx + 2];
  }
}

// ---------------- K2: KNN-16 + feature gather (16 supernodes per block) ----------------
#define NTHR2 256
#define CH 2048
#define LSD 258   // padded per-supernode stride (doubles) to break bank conflicts
#define LSI 257

__global__ __launch_bounds__(256)
void knn_kernel(const float* __restrict__ x, const float* __restrict__ xyz,
                const void* __restrict__ validp, const int* __restrict__ flagp,
                float* __restrict__ out) {
  __shared__ __align__(16) char smem[16 * LSD * 8 + 16 * LSI * 4];  // 49472 B, unioned
  float* raw = (float*)smem;                       // CH*3 floats (24 KB)
  double* sbd = (double*)(smem + CH * 3 * 4);      // CH doubles (16 KB)
  double* ld2 = (double*)smem;                     // merge phase: 16*LSD doubles
  int* lidx = (int*)(smem + 16 * LSD * 8);         // merge phase: 16*LSI ints
  __shared__ double wn_d[256];
  __shared__ int wn_i[256];

  const int b = blockIdx.x >> 6;
  const int grp = blockIdx.x & 63;
  const int t = threadIdx.x;
  const int sl = t & 15;       // supernode within group
  const int slice = t >> 4;    // point slice 0..15
  const int m = grp * 16 + sl;
  const int vmode = flagp[0];
  const float* xyzb = xyz + (size_t)b * NPTS * 3;

  const int sidx = (int)out[O3 + (size_t)b * M_SN + m];
  const double dax = (double)xyzb[3 * sidx + 0];
  const double day = (double)xyzb[3 * sidx + 1];
  const double daz = (double)xyzb[3 * sidx + 2];
  const double sa = dax * dax + day * day + daz * daz;

  double bd[16];
  int bi[16];
#pragma unroll
  for (int q = 0; q < 16; q++) { bd[q] = (double)INFINITY; bi[q] = 0x7FFFFFFF; }

  for (int c0 = 0; c0 < NPTS; c0 += CH) {
    for (int j = t; j < CH * 3; j += NTHR2) raw[j] = xyzb[(size_t)c0 * 3 + j];
    __syncthreads();
    for (int p = t; p < CH; p += NTHR2) {
      double px = raw[3 * p], py = raw[3 * p + 1], pz = raw[3 * p + 2];
      bool v = is_valid_el(validp, vmode, (long long)b * NPTS + c0 + p);
      sbd[p] = v ? (px * px + py * py + pz * pz) : (double)INFINITY;
    }
    __syncthreads();
    for (int j = 0; j < CH / 16; j++) {
      int p = slice + 16 * j;
      double px = (double)raw[3 * p], py = (double)raw[3 * p + 1], pz = (double)raw[3 * p + 2];
      double dot = dax * px + day * py + daz * pz;
      double d2 = (sa + sbd[p]) - 2.0 * dot;
      if (d2 < 0.0) d2 = 0.0;
      int gi = c0 + p;
      if ((d2 < bd[15]) || (d2 == bd[15] && gi < bi[15])) {
        double cd = d2; int ci = gi;
#pragma unroll
        for (int q = 0; q < 16; q++) {
          bool lt = (cd < bd[q]) || (cd == bd[q] && ci < bi[q]);
          if (lt) { double td = bd[q]; int ti = bi[q]; bd[q] = cd; bi[q] = ci; cd = td; ci = ti; }
        }
      }
    }
    __syncthreads();
  }

  // dump per-thread sorted lists
#pragma unroll
  for (int q = 0; q < 16; q++) {
    ld2[sl * LSD + slice * 16 + q] = bd[q];
    lidx[sl * LSI + slice * 16 + q] = bi[q];
  }
  __syncthreads();

  // merge: exact rank of each local entry among the 256 of its supernode (early exit, lists sorted)
#pragma unroll 1
  for (int q = 0; q < 16; q++) {
    double d = bd[q];
    int ix = bi[q];
    int r = q;  // own list contributes q smaller entries
    for (int os = 0; os < 16 && r < 16; ++os) {
      if (os == slice) continue;
      const double* pd = &ld2[sl * LSD + os * 16];
      const int* pi = &lidx[sl * LSI + os * 16];
      for (int e = 0; e < 16; e++) {
        double od = pd[e];
        bool less = (od < d) || (od == d && pi[e] < ix);
        if (!less) break;
        r++;
      }
    }
    if (r < 16) { wn_d[sl * 16 + r] = d; wn_i[sl * 16 + r] = ix; }
  }
  __syncthreads();

  // emit neighbor_mask + gather features
  {
    int s2 = t >> 4;
    int k2 = t & 15;
    int mm = grp * 16 + s2;
    double d = wn_d[s2 * 16 + k2];
    int ni = wn_i[s2 * 16 + k2];
    size_t o2 = ((size_t)b * M_SN + mm) * KNN + k2;
    out[O2 + o2] = (d == (double)INFINITY) ? 0.0f : 1.0f;
    const float4* src = (const float4*)(x + ((size_t)b * NPTS + ni) * CCH);
    float4* dst = (float4*)(out + O0 + o2 * CCH);
#pragma unroll
    for (int q = 0; q < 16; q++) dst[q] = src[q];
  }
}

extern "C" void kernel_launch(void* const* d_in, const int* in_sizes, int n_in,
                              void* d_out, int out_size, void* d_ws, size_t ws_size,
                              hipStream_t stream) {
  const float* x = (const float*)d_in[0];
  const float* xyz = (const float*)d_in[1];
  const void* valid = d_in[2];
  const float* state = (const float*)d_in[3];
  const int* mask_id = (const int*)d_in[4];
  const float* extra = (const float*)d_in[5];
  const float* glob = (const float*)d_in[6];
  float* out = (float*)d_out;
  int* flag = (int*)d_ws;

  detect_valid<<<1, 1024, 0, stream>>>((const unsigned*)valid, in_sizes[2] / 4, flag);
  sample_kernel<<<BF, NTHR1, 0, stream>>>(xyz, valid, state, mask_id, extra, glob, flag, out);
  knn_kernel<<<BF * 64, NTHR2, 0, stream>>>(x, xyz, valid, flag, out);
}

// Round 2
// 593.149 us; speedup vs baseline: 2.5729x; 2.5729x over previous
//
#include <hip/hip_runtime.h>
#include <math.h>

typedef unsigned long long u64;
typedef unsigned int u32;

#define BF 8
#define NPTS 16384
#define M_SN 1024
#define CCH 64
#define KNN 16
#define NTHR1 1024
#define KPER 16            // NPTS / NTHR1
#define TBL 4096
#define CCAP 3072
#define REM 1008           // M - 16 gripper slots

// output layout (flat float32, concatenated in return order)
constexpr size_t O0 = 0;                 // neighbor_feats 8*1024*16*64
constexpr size_t O1 = 8388608;           // supernode_xyz 8*1024*3
constexpr size_t O2 = 8413184;           // neighbor_mask 8*1024*16
constexpr size_t O3 = 8544256;           // out_idx 8*1024
constexpr size_t O4 = 8552448;           // out_valid 8*1024
constexpr size_t O5 = 8560640;           // out_bucket 8*1024

__device__ __forceinline__ bool is_valid_el(const void* vp, int mode, long long i) {
  if (mode == 1) return ((const unsigned char*)vp)[i] != 0;
  if (mode == 2) return ((const float*)vp)[i] != 0.0f;
  return ((const int*)vp)[i] != 0;
}

// monotone-decreasing encode: larger float -> smaller u32 (NaN sorts first; -inf last)
__device__ __forceinline__ u32 desc_enc(float f) {
  u32 u = __float_as_uint(f);
  u32 s = (u & 0x80000000u) ? ~u : (u | 0x80000000u);
  return ~s;
}
__device__ __forceinline__ bool enc_finite(u32 d) {
  u32 s = ~d;
  u32 u = (s & 0x80000000u) ? (s & 0x7FFFFFFFu) : ~s;
  return (u & 0x7F800000u) != 0x7F800000u;
}

__device__ __forceinline__ u64 wave_min_u64(u64 v) {
#pragma unroll
  for (int d = 32; d >= 1; d >>= 1) {
    u32 lo = __shfl_xor((u32)(v & 0xFFFFFFFFu), d, 64);
    u32 hi = __shfl_xor((u32)(v >> 32), d, 64);
    u64 o = ((u64)hi << 32) | lo;
    if (o < v) v = o;
  }
  return v;
}

// block-wide min over 1024 threads; red16 is a dedicated u64[16] LDS array
__device__ __forceinline__ u64 block_min_u64(u64 v, u64* red16, int t) {
  v = wave_min_u64(v);
  if ((t & 63) == 0) red16[t >> 6] = v;
  __syncthreads();
  if (t < 64) {
    u64 x = red16[t & 15];
    x = wave_min_u64(x);
    if (t == 0) red16[0] = x;
  }
  __syncthreads();
  u64 r = red16[0];
  __syncthreads();
  return r;
}

// ---------------- K0: detect how `valid` (bool) is stored ----------------
__global__ void detect_valid(const unsigned* __restrict__ w, int nwords, int* __restrict__ flag) {
  __shared__ int cls;
  int t = threadIdx.x;
  if (t == 0) cls = 0;
  __syncthreads();
  int local = 0;
  for (int i = t; i < nwords; i += blockDim.x) {
    unsigned v = w[i];
    if (v == 0x3F800000u) local = 2;            // float32 storage
    else if (v != 0u && v != 1u) local = max(local, 1); // packed bytes
  }
  if (local) atomicMax(&cls, local);
  __syncthreads();
  if (t == 0) flag[0] = cls;                    // 0=int32, 1=uint8, 2=float32
}

// ---------------- K1: supernode sampling (one block per batch row) ----------------
__global__ __launch_bounds__(1024)
void sample_kernel(const float* __restrict__ xyz, const void* __restrict__ validp,
                   const float* __restrict__ state, const int* __restrict__ mask_id,
                   const float* __restrict__ extra, const float* __restrict__ glob,
                   const int* __restrict__ flagp, float* __restrict__ out) {
  __shared__ u64 red16[16];
  __shared__ int table[TBL];        // 16 KB (mask min-index table, reused as histogram)
  __shared__ int scanb[NTHR1];      // 4 KB
  __shared__ int mpick[REM];        // ~4 KB
  __shared__ u64 cand[CCAP];        // 24 KB
  __shared__ int gsorted[REM];      // ~4 KB
  __shared__ int head_i[16];
  __shared__ int head_bk[16];
  __shared__ int sh[8];             // 0:rhv 1:first_valid 2:has_radius 3:nmask_total 4:n_avail 5:cand_cnt 6:B

  const int b = blockIdx.x, t = threadIdx.x;
  const int vmode = flagp[0];
  const float* xyzb = xyz + (size_t)b * NPTS * 3;
  const int* midb = mask_id + (size_t)b * NPTS;
  const float* exb = extra + (size_t)b * NPTS;
  const float* glb = glob + (size_t)b * NPTS;

  if (t < 8) sh[t] = 0;
  if (t == 1) sh[1] = 0x7FFFFFFF;
  if (t == 6) sh[6] = 0x7FFFFFFF;
  __syncthreads();

  // ---- validity bits (element i = k*1024 + t) ----
  u32 vbits = 0;
#pragma unroll
  for (int k = 0; k < KPER; k++) {
    int i = k * NTHR1 + t;
    if (is_valid_el(validp, vmode, (long long)b * NPTS + i)) vbits |= 1u << k;
  }
  if (vbits) {
    atomicOr(&sh[0], 1);
    atomicMin(&sh[1], (__ffs(vbits) - 1) * NTHR1 + t);
  }

  // ---- gripper distances ----
  float gx = state[b * 8 + 0], gy = state[b * 8 + 1], gz = state[b * 8 + 2];
  float gd[KPER];
  u32 inr = 0;
#pragma unroll
  for (int k = 0; k < KPER; k++) {
    int i = k * NTHR1 + t;
    float dx = xyzb[3 * i] - gx, dy = xyzb[3 * i + 1] - gy, dz = xyzb[3 * i + 2] - gz;
    float d = sqrtf((dx * dx + dy * dy) + dz * dz);
    gd[k] = d;
    if (((vbits >> k) & 1u) && d <= 0.1f) inr |= 1u << k;
  }
  if (inr) atomicOr(&sh[2], 1);
  __syncthreads();

  const int rhv = sh[0];
  const int first_valid = rhv ? sh[1] : 0;
  const u32 elig = vbits & (sh[2] ? inr : 0xFFFFu);
  u32 sel = 0;

  // ---- 16 gripper picks: iterative argmin of (gdist, idx) over eligible ----
  for (int it = 0; it < 16; ++it) {
    u64 best = ~0ull;
#pragma unroll
    for (int k = 0; k < KPER; k++) {
      if (((elig >> k) & 1u) && !((sel >> k) & 1u)) {
        u64 key = ((u64)__float_as_uint(gd[k]) << 32) | (u32)(k * NTHR1 + t);
        if (key < best) best = key;
      }
    }
    u64 w = block_min_u64(best, red16, t);
    bool keep = (w >> 32) < 0x7F800000ull;   // finite distance found
    int idx = (int)(w & 0xFFFFFFFFu);
    if (t == 0) { head_i[it] = keep ? idx : first_valid; head_bk[it] = keep ? 1 : -1; }
    if (keep && (idx & (NTHR1 - 1)) == t) sel |= 1u << (idx >> 10);
  }

  // ---- mask stage: min index per distinct mask_id among candidates ----
  for (int j = t; j < TBL; j += NTHR1) table[j] = 0x7FFFFFFF;
  __syncthreads();
#pragma unroll
  for (int k = 0; k < KPER; k++) {
    if (((vbits >> k) & 1u) && !((sel >> k) & 1u)) {
      int i = k * NTHR1 + t;
      int id = midb[i];
      if ((u32)id < TBL) atomicMin(&table[id], i);
    }
  }
  __syncthreads();
  int cnt = 0;
#pragma unroll
  for (int q = 0; q < 4; q++) cnt += (table[4 * t + q] != 0x7FFFFFFF);
  scanb[t] = cnt;
  __syncthreads();
  for (int off = 1; off < NTHR1; off <<= 1) {
    int v = (t >= off) ? scanb[t - off] : 0;
    __syncthreads();
    scanb[t] += v;
    __syncthreads();
  }
  {
    int excl = scanb[t] - cnt;
    if (t == NTHR1 - 1) sh[3] = scanb[t];
    int pos = excl;
#pragma unroll
    for (int q = 0; q < 4; q++) {
      int v = table[4 * t + q];
      if (v != 0x7FFFFFFF) { if (pos < REM) mpick[pos] = v; pos++; }
    }
  }
  __syncthreads();
  const int nm = min(sh[3], REM);
  for (int j = 0; j < nm; j++) {
    int p = mpick[j];
    if ((p & (NTHR1 - 1)) == t) sel |= 1u << (p >> 10);
  }

  // ---- extra stage (only active when < 8 distinct mask ids) ----
  u32 extra_used = 0;
  if (nm < 8 && rhv) {
    u32 extrbits = 0;
    for (int j = 0; j < 8; j++) {
      u64 best = ~0ull;
#pragma unroll
      for (int k = 0; k < KPER; k++) {
        if (((vbits >> k) & 1u) && !((sel >> k) & 1u) && !((extrbits >> k) & 1u)) {
          int i = k * NTHR1 + t;
          u64 key = ((u64)desc_enc(exb[i]) << 32) | (u32)i;
          if (key < best) best = key;
        }
      }
      u64 w = block_min_u64(best, red16, t);
      if (w == ~0ull) break;                  // uniform: no candidates left
      int idx = (int)(w & 0xFFFFFFFFu);
      bool fin = enc_finite((u32)(w >> 32));
      if ((idx & (NTHR1 - 1)) == t) extrbits |= 1u << (idx >> 10);
      if (j >= nm && fin) {
        extra_used |= 1u << j;
        if (t == 0) mpick[j] = idx;
        if ((idx & (NTHR1 - 1)) == t) sel |= 1u << (idx >> 10);
      }
    }
    __syncthreads();
  }

  // ---- global stage: exact ordered top-1008 of (global_score desc, idx asc) ----
  for (int j = t; j < TBL; j += NTHR1) table[j] = 0;
  for (int j = t; j < REM; j += NTHR1) gsorted[j] = -1;
  __syncthreads();
  u32 cbits = vbits & ~sel;
  atomicAdd(&sh[4], __popc(cbits));
  u32 dk[KPER];
#pragma unroll
  for (int k = 0; k < KPER; k++) {
    if ((cbits >> k) & 1u) {
      dk[k] = desc_enc(glb[k * NTHR1 + t]);
      atomicAdd(&table[dk[k] >> 20], 1);
    }
  }
  __syncthreads();
  const int nav = sh[4];
  const int T = min(REM, nav);
  if (T > 0) {
    int c4 = table[4 * t] + table[4 * t + 1] + table[4 * t + 2] + table[4 * t + 3];
    scanb[t] = c4;
    __syncthreads();
    for (int off = 1; off < NTHR1; off <<= 1) {
      int v = (t >= off) ? scanb[t - off] : 0;
      __syncthreads();
      scanb[t] += v;
      __syncthreads();
    }
    int cum = scanb[t] - c4;
#pragma unroll
    for (int q = 0; q < 4; q++) {
      int prev = cum;
      cum += table[4 * t + q];
      if (prev < T && cum >= T) atomicMin(&sh[6], 4 * t + q);
    }
    __syncthreads();
    const int B = sh[6];
#pragma unroll
    for (int k = 0; k < KPER; k++) {
      if (((cbits >> k) & 1u) && (int)(dk[k] >> 20) <= B) {
        int pos = atomicAdd(&sh[5], 1);
        if (pos < CCAP) cand[pos] = ((u64)dk[k] << 32) | (u32)(k * NTHR1 + t);
      }
    }
    __syncthreads();
    int nc = min(sh[5], CCAP);
    if (sh[5] <= CCAP) {
      // exact rank by counting (keys unique: idx is in low bits)
      for (int c = t; c < nc; c += NTHR1) {
        u64 key = cand[c];
        int r = 0;
        for (int j = 0; j < nc; j++) r += (cand[j] < key);
        if (r < REM) {
          int ix = (int)(key & 0xFFFFFFFFu);
          gsorted[r] = enc_finite((u32)(key >> 32)) ? ix : (ix | (int)0x80000000);
        }
      }
    } else {
      // pathological-ties fallback: iterative extraction (never triggers on bench data)
      u32 gext = 0;
      for (int j = 0; j < T; j++) {
        u64 best = ~0ull;
#pragma unroll
        for (int k = 0; k < KPER; k++) {
          if (((cbits >> k) & 1u) && !((gext >> k) & 1u)) {
            u64 key = ((u64)dk[k] << 32) | (u32)(k * NTHR1 + t);
            if (key < best) best = key;
          }
        }
        u64 w = block_min_u64(best, red16, t);
        if (w == ~0ull) break;
        int idx = (int)(w & 0xFFFFFFFFu);
        if ((idx & (NTHR1 - 1)) == t) gext |= 1u << (idx >> 10);
        if (t == 0) gsorted[j] = enc_finite((u32)(w >> 32)) ? idx : (idx | (int)0x80000000);
      }
    }
    __syncthreads();
  }

  // ---- emit out_idx / out_valid / out_bucket / supernode_xyz ----
  {
    int slot = t;
    int idx, bucket;
    if (slot < 16) {
      idx = head_i[slot];
      bucket = head_bk[slot];
    } else {
      int jj = slot - 16;
      bool mk = (jj < nm) || (jj < 8 && ((extra_used >> jj) & 1u));
      if (mk) { idx = mpick[jj]; bucket = 2; }
      else {
        int g = gsorted[jj];
        if (rhv && g >= 0) { idx = g; bucket = 0; }
        else { idx = first_valid; bucket = -1; }
      }
    }
    bool ov = rhv && is_valid_el(validp, vmode, (long long)b * NPTS + idx);
    int ob = ov ? bucket : -1;
    size_t o = (size_t)b * M_SN + slot;
    out[O3 + o] = (float)idx;
    out[O4 + o] = ov ? 1.0f : 0.0f;
    out[O5 + o] = (float)ob;
    out[O1 + 3 * o + 0] = xyzb[3 * idx + 0];
    out[O1 + 3 * o + 1] = xyzb[3 * idx + 1];
    out[O1 + 3 * o + 2] = xyzb[3 * idx + 2];
  }
}

// ---------------- K2: KNN-16 + feature gather ----------------
// 8 supernodes per block of 256 threads; 32 point-slices per supernode.
// fp32 d2 (mirrors reference arithmetic, no FMA contraction), u64 key = (d2_bits<<32)|idx.
// Per-lane 8-deep LDS candidate buffer amortizes the top-16 insertion chain
// (wave-divergence made the chain fire every iteration without buffering).
#define NTHR2 256
#define CH 1024
#define SPB 8      // supernodes per block
#define SLICES 32  // threads per supernode
#define BUFD 8     // per-lane buffer depth
#define LSTRIDE 17 // padded list stride (u64) for merge phase

__global__ __launch_bounds__(256)
void knn_kernel(const float* __restrict__ x, const float* __restrict__ xyz,
                const void* __restrict__ validp, const int* __restrict__ flagp,
                float* __restrict__ out) {
  // blob: stage phase: [0,2048) u64 = float4 stage[CH]; [2048,2048+BUFD*256) = buffers
  // merge phase: lists, (SPB*SLICES)*LSTRIDE u64 = 4352
  __shared__ __align__(16) u64 blob[4352];          // 34 KB
  __shared__ u64 wn[SPB * KNN];                     // winners per supernode

  float4* st = (float4*)blob;
  u64* buf = blob + 2048;

  const int b = blockIdx.x >> 7;
  const int grp = blockIdx.x & 127;
  const int t = threadIdx.x;
  const int sl = t & (SPB - 1);      // supernode within group
  const int slice = t >> 3;          // 0..31
  const int m = grp * SPB + sl;
  const int vmode = flagp[0];
  const float* xyzb = xyz + (size_t)b * NPTS * 3;

  const int sidx = (int)out[O3 + (size_t)b * M_SN + m];
  const float ax = xyzb[3 * sidx + 0];
  const float ay = xyzb[3 * sidx + 1];
  const float az = xyzb[3 * sidx + 2];
  const float sa = __fadd_rn(__fadd_rn(__fmul_rn(ax, ax), __fmul_rn(ay, ay)), __fmul_rn(az, az));

  u64 best[16];
#pragma unroll
  for (int q = 0; q < 16; q++) best[q] = ~0ull;
  int cnt = 0;

  for (int c0 = 0; c0 < NPTS; c0 += CH) {
    // stage CH points as float4 {x,y,z,|b|^2 or inf}
    for (int p = t; p < CH; p += NTHR2) {
      float px = xyzb[3 * (c0 + p)], py = xyzb[3 * (c0 + p) + 1], pz = xyzb[3 * (c0 + p) + 2];
      bool v = is_valid_el(validp, vmode, (long long)b * NPTS + c0 + p);
      float sb = __fadd_rn(__fadd_rn(__fmul_rn(px, px), __fmul_rn(py, py)), __fmul_rn(pz, pz));
      st[p] = make_float4(px, py, pz, v ? sb : INFINITY);
    }
    __syncthreads();
#pragma unroll 4
    for (int j = 0; j < CH / SLICES; j++) {
      int p = slice + SLICES * j;
      float4 v = st[p];
      float dot = __fadd_rn(__fadd_rn(__fmul_rn(ax, v.x), __fmul_rn(ay, v.y)), __fmul_rn(az, v.z));
      float d2 = __fsub_rn(__fadd_rn(sa, v.w), __fmul_rn(2.0f, dot));
      d2 = fmaxf(d2, 0.0f);
      u64 key = ((u64)__float_as_uint(d2) << 32) | (u32)(c0 + p);
      if (key < best[15]) {
        buf[cnt * NTHR2 + t] = key;
        cnt++;
      }
      if (__any(cnt == BUFD)) {
        int n = cnt;
        for (int c = 0; c < n; c++) {
          u64 k2 = buf[c * NTHR2 + t];
          if (k2 < best[15]) {
#pragma unroll
            for (int q = 0; q < 16; q++) {
              bool lt = k2 < best[q];
              u64 mn = lt ? k2 : best[q];
              u64 mx = lt ? best[q] : k2;
              best[q] = mn; k2 = mx;
            }
          }
        }
        cnt = 0;
      }
    }
    __syncthreads();
  }
  // final flush
  {
    int n = cnt;
    for (int c = 0; c < n; c++) {
      u64 k2 = buf[c * NTHR2 + t];
      if (k2 < best[15]) {
#pragma unroll
        for (int q = 0; q < 16; q++) {
          bool lt = k2 < best[q];
          u64 mn = lt ? k2 : best[q];
          u64 mx = lt ? best[q] : k2;
          best[q] = mn; k2 = mx;
        }
      }
    }
  }
  __syncthreads();

  // dump per-thread sorted lists (padded stride to break bank conflicts)
  {
    u64* my = blob + (size_t)(sl * SLICES + slice) * LSTRIDE;
#pragma unroll
    for (int q = 0; q < 16; q++) my[q] = best[q];
  }
  __syncthreads();

  // merge: exact rank of each local entry among the supernode's 512 (early exit, lists sorted)
#pragma unroll 1
  for (int q = 0; q < 16; q++) {
    u64 key = best[q];
    int r = q;  // own list contributes q smaller entries
    for (int os = 0; os < SLICES && r < 16; ++os) {
      if (os == slice) continue;
      const u64* pl = blob + (size_t)(sl * SLICES + os) * LSTRIDE;
#pragma unroll 1
      for (int e = 0; e < 16; e++) {
        if (pl[e] >= key) break;
        r++;
      }
    }
    if (r < 16) wn[sl * KNN + r] = key;
  }
  __syncthreads();

  // emit neighbor_mask + gather features (2 threads per (supernode,k) row)
  {
    int s2 = t >> 5;            // 0..7
    int k2 = (t >> 1) & 15;     // 0..15
    int half = t & 1;
    int mm = grp * SPB + s2;
    u64 key = wn[s2 * KNN + k2];
    int ni = (int)(key & 0xFFFFFFFFu);
    size_t o2 = ((size_t)b * M_SN + mm) * KNN + k2;
    if (half == 0) out[O2 + o2] = ((u32)(key >> 32) < 0x7F800000u) ? 1.0f : 0.0f;
    const float4* src = (const float4*)(x + ((size_t)b * NPTS + ni) * CCH);
    float4* dst = (float4*)(out + O0 + o2 * CCH);
#pragma unroll
    for (int q = 0; q < 8; q++) dst[half * 8 + q] = src[half * 8 + q];
  }
}

extern "C" void kernel_launch(void* const* d_in, const int* in_sizes, int n_in,
                              void* d_out, int out_size, void* d_ws, size_t ws_size,
                              hipStream_t stream) {
  const float* x = (const float*)d_in[0];
  const float* xyz = (const float*)d_in[1];
  const void* valid = d_in[2];
  const float* state = (const float*)d_in[3];
  const int* mask_id = (const int*)d_in[4];
  const float* extra = (const float*)d_in[5];
  const float* glob = (const float*)d_in[6];
  float* out = (float*)d_out;
  int* flag = (int*)d_ws;

  detect_valid<<<1, 1024, 0, stream>>>((const unsigned*)valid, in_sizes[2] / 4, flag);
  sample_kernel<<<BF, NTHR1, 0, stream>>>(xyz, valid, state, mask_id, extra, glob, flag, out);
  knn_kernel<<<BF * 128, NTHR2, 0, stream>>>(x, xyz, valid, flag, out);
}

// Round 3
// 550.835 us; speedup vs baseline: 2.7705x; 1.0768x over previous
//
#include <hip/hip_runtime.h>
#include <math.h>

typedef unsigned long long u64;
typedef unsigned int u32;

#define BF 8
#define NPTS 16384
#define M_SN 1024
#define CCH 64
#define KNN 16
#define NTHR1 1024
#define KPER 16            // NPTS / NTHR1
#define TBL 4096
#define CCAP 3072
#define REM 1008           // M - 16 gripper slots

// output layout (flat float32, concatenated in return order)
constexpr size_t O0 = 0;                 // neighbor_feats 8*1024*16*64
constexpr size_t O1 = 8388608;           // supernode_xyz 8*1024*3
constexpr size_t O2 = 8413184;           // neighbor_mask 8*1024*16
constexpr size_t O3 = 8544256;           // out_idx 8*1024
constexpr size_t O4 = 8552448;           // out_valid 8*1024
constexpr size_t O5 = 8560640;           // out_bucket 8*1024

__device__ __forceinline__ bool is_valid_el(const void* vp, int mode, long long i) {
  if (mode == 1) return ((const unsigned char*)vp)[i] != 0;
  if (mode == 2) return ((const float*)vp)[i] != 0.0f;
  return ((const int*)vp)[i] != 0;
}

// monotone-decreasing encode: larger float -> smaller u32 (NaN sorts first; -inf last)
__device__ __forceinline__ u32 desc_enc(float f) {
  u32 u = __float_as_uint(f);
  u32 s = (u & 0x80000000u) ? ~u : (u | 0x80000000u);
  return ~s;
}
__device__ __forceinline__ bool enc_finite(u32 d) {
  u32 s = ~d;
  u32 u = (s & 0x80000000u) ? (s & 0x7FFFFFFFu) : ~s;
  return (u & 0x7F800000u) != 0x7F800000u;
}

__device__ __forceinline__ u64 wave_min_u64(u64 v) {
#pragma unroll
  for (int d = 32; d >= 1; d >>= 1) {
    u32 lo = __shfl_xor((u32)(v & 0xFFFFFFFFu), d, 64);
    u32 hi = __shfl_xor((u32)(v >> 32), d, 64);
    u64 o = ((u64)hi << 32) | lo;
    if (o < v) v = o;
  }
  return v;
}

// block-wide min over 1024 threads; red16 is a dedicated u64[16] LDS array
__device__ __forceinline__ u64 block_min_u64(u64 v, u64* red16, int t) {
  v = wave_min_u64(v);
  if ((t & 63) == 0) red16[t >> 6] = v;
  __syncthreads();
  if (t < 64) {
    u64 x = red16[t & 15];
    x = wave_min_u64(x);
    if (t == 0) red16[0] = x;
  }
  __syncthreads();
  u64 r = red16[0];
  __syncthreads();
  return r;
}

// exclusive prefix-sum of val across 1024 threads (2 barriers + trailing reuse barrier)
__device__ __forceinline__ int block_excl_scan(int val, int* scanb, int t, int* tot) {
  int incl = val;
#pragma unroll
  for (int d = 1; d < 64; d <<= 1) {
    int v = __shfl_up(incl, d, 64);
    if ((t & 63) >= d) incl += v;
  }
  if ((t & 63) == 63) scanb[t >> 6] = incl;
  __syncthreads();
  if (t < 64) {
    int ws = (t < 16) ? scanb[t] : 0;
#pragma unroll
    for (int d = 1; d < 16; d <<= 1) {
      int v = __shfl_up(ws, d, 64);
      if ((t & 63) >= d) ws += v;
    }
    if (t < 16) scanb[16 + t] = ws;
  }
  __syncthreads();
  int wv = t >> 6;
  int base = (wv == 0) ? 0 : scanb[16 + wv - 1];
  *tot = scanb[16 + 15];
  int r = base + incl - val;
  __syncthreads();   // scanb reusable after return
  return r;
}

// ---------------- K0: detect how `valid` (bool) is stored ----------------
__global__ void detect_valid(const unsigned* __restrict__ w, int nwords, int* __restrict__ flag) {
  __shared__ int cls;
  int t = threadIdx.x;
  if (t == 0) cls = 0;
  __syncthreads();
  int local = 0;
  for (int i = t; i < nwords; i += blockDim.x) {
    unsigned v = w[i];
    if (v == 0x3F800000u) local = 2;            // float32 storage
    else if (v != 0u && v != 1u) local = max(local, 1); // packed bytes
  }
  if (local) atomicMax(&cls, local);
  __syncthreads();
  if (t == 0) flag[0] = cls;                    // 0=int32, 1=uint8, 2=float32
}

// ---------------- K1: supernode sampling (one block per batch row) ----------------
__global__ __launch_bounds__(1024)
void sample_kernel(const float* __restrict__ xyz, const void* __restrict__ validp,
                   const float* __restrict__ state, const int* __restrict__ mask_id,
                   const float* __restrict__ extra, const float* __restrict__ glob,
                   const int* __restrict__ flagp, float* __restrict__ out) {
  __shared__ u64 red16[16];
  __shared__ int table[TBL];        // 16 KB (mask min-index table, reused as histogram)
  __shared__ int scanb[32];
  __shared__ int mpick[REM];        // ~4 KB
  __shared__ u64 cand[CCAP];        // 24 KB
  __shared__ int gsorted[REM];      // ~4 KB
  __shared__ int head_i[16];
  __shared__ int head_bk[16];
  __shared__ int sh[8];             // 0:rhv 1:first_valid 2:has_radius 4:n_avail 5:cand_cnt 6:B

  const int b = blockIdx.x, t = threadIdx.x;
  const int vmode = flagp[0];
  const float* xyzb = xyz + (size_t)b * NPTS * 3;
  const int* midb = mask_id + (size_t)b * NPTS;
  const float* exb = extra + (size_t)b * NPTS;
  const float* glb = glob + (size_t)b * NPTS;

  if (t < 8) sh[t] = 0;
  if (t == 1) sh[1] = 0x7FFFFFFF;
  if (t == 6) sh[6] = 0x7FFFFFFF;
  __syncthreads();

  // ---- validity bits (element i = k*1024 + t) ----
  u32 vbits = 0;
#pragma unroll
  for (int k = 0; k < KPER; k++) {
    int i = k * NTHR1 + t;
    if (is_valid_el(validp, vmode, (long long)b * NPTS + i)) vbits |= 1u << k;
  }
  if (vbits) {
    atomicOr(&sh[0], 1);
    atomicMin(&sh[1], (__ffs(vbits) - 1) * NTHR1 + t);
  }

  // ---- gripper distances ----
  float gx = state[b * 8 + 0], gy = state[b * 8 + 1], gz = state[b * 8 + 2];
  float gd[KPER];
  u32 inr = 0;
#pragma unroll
  for (int k = 0; k < KPER; k++) {
    int i = k * NTHR1 + t;
    float dx = xyzb[3 * i] - gx, dy = xyzb[3 * i + 1] - gy, dz = xyzb[3 * i + 2] - gz;
    float d = sqrtf((dx * dx + dy * dy) + dz * dz);
    gd[k] = d;
    if (((vbits >> k) & 1u) && d <= 0.1f) inr |= 1u << k;
  }
  if (inr) atomicOr(&sh[2], 1);
  __syncthreads();

  const int rhv = sh[0];
  const int first_valid = rhv ? sh[1] : 0;
  const u32 elig = vbits & (sh[2] ? inr : 0xFFFFu);
  u32 sel = 0;

  // ---- 16 gripper picks: iterative argmin of (gdist, idx) over eligible ----
  for (int it = 0; it < 16; ++it) {
    u64 best = ~0ull;
#pragma unroll
    for (int k = 0; k < KPER; k++) {
      if (((elig >> k) & 1u) && !((sel >> k) & 1u)) {
        u64 key = ((u64)__float_as_uint(gd[k]) << 32) | (u32)(k * NTHR1 + t);
        if (key < best) best = key;
      }
    }
    u64 w = block_min_u64(best, red16, t);
    bool keep = (w >> 32) < 0x7F800000ull;   // finite distance found
    int idx = (int)(w & 0xFFFFFFFFu);
    if (t == 0) { head_i[it] = keep ? idx : first_valid; head_bk[it] = keep ? 1 : -1; }
    if (keep && (idx & (NTHR1 - 1)) == t) sel |= 1u << (idx >> 10);
  }

  // ---- mask stage: min index per distinct mask_id among candidates ----
  for (int j = t; j < TBL; j += NTHR1) table[j] = 0x7FFFFFFF;
  __syncthreads();
#pragma unroll
  for (int k = 0; k < KPER; k++) {
    if (((vbits >> k) & 1u) && !((sel >> k) & 1u)) {
      int i = k * NTHR1 + t;
      int id = midb[i];
      if ((u32)id < TBL) atomicMin(&table[id], i);
    }
  }
  __syncthreads();
  int cnt = 0;
#pragma unroll
  for (int q = 0; q < 4; q++) cnt += (table[4 * t + q] != 0x7FFFFFFF);
  int mtot;
  int excl = block_excl_scan(cnt, scanb, t, &mtot);
  {
    int pos = excl;
#pragma unroll
    for (int q = 0; q < 4; q++) {
      int v = table[4 * t + q];
      if (v != 0x7FFFFFFF) { if (pos < REM) mpick[pos] = v; pos++; }
    }
  }
  __syncthreads();
  const int nm = min(mtot, REM);
  for (int j = 0; j < nm; j++) {
    int p = mpick[j];
    if ((p & (NTHR1 - 1)) == t) sel |= 1u << (p >> 10);
  }

  // ---- extra stage (only active when < 8 distinct mask ids) ----
  u32 extra_used = 0;
  if (nm < 8 && rhv) {
    u32 extrbits = 0;
    for (int j = 0; j < 8; j++) {
      u64 best = ~0ull;
#pragma unroll
      for (int k = 0; k < KPER; k++) {
        if (((vbits >> k) & 1u) && !((sel >> k) & 1u) && !((extrbits >> k) & 1u)) {
          int i = k * NTHR1 + t;
          u64 key = ((u64)desc_enc(exb[i]) << 32) | (u32)i;
          if (key < best) best = key;
        }
      }
      u64 w = block_min_u64(best, red16, t);
      if (w == ~0ull) break;                  // uniform: no candidates left
      int idx = (int)(w & 0xFFFFFFFFu);
      bool fin = enc_finite((u32)(w >> 32));
      if ((idx & (NTHR1 - 1)) == t) extrbits |= 1u << (idx >> 10);
      if (j >= nm && fin) {
        extra_used |= 1u << j;
        if (t == 0) mpick[j] = idx;
        if ((idx & (NTHR1 - 1)) == t) sel |= 1u << (idx >> 10);
      }
    }
    __syncthreads();
  }

  // ---- global stage: exact ordered top-1008 of (global_score desc, idx asc) ----
  for (int j = t; j < TBL; j += NTHR1) table[j] = 0;
  for (int j = t; j < REM; j += NTHR1) gsorted[j] = -1;
  __syncthreads();
  u32 cbits = vbits & ~sel;
  atomicAdd(&sh[4], __popc(cbits));
  u32 dk[KPER];
#pragma unroll
  for (int k = 0; k < KPER; k++) {
    if ((cbits >> k) & 1u) {
      dk[k] = desc_enc(glb[k * NTHR1 + t]);
      atomicAdd(&table[dk[k] >> 20], 1);
    }
  }
  __syncthreads();
  const int nav = sh[4];
  const int T = min(REM, nav);
  if (T > 0) {
    int c4 = table[4 * t] + table[4 * t + 1] + table[4 * t + 2] + table[4 * t + 3];
    int htot;
    int cum = block_excl_scan(c4, scanb, t, &htot);
#pragma unroll
    for (int q = 0; q < 4; q++) {
      int prev = cum;
      cum += table[4 * t + q];
      if (prev < T && cum >= T) atomicMin(&sh[6], 4 * t + q);
    }
    __syncthreads();
    const int B = sh[6];
#pragma unroll
    for (int k = 0; k < KPER; k++) {
      if (((cbits >> k) & 1u) && (int)(dk[k] >> 20) <= B) {
        int pos = atomicAdd(&sh[5], 1);
        if (pos < CCAP) cand[pos] = ((u64)dk[k] << 32) | (u32)(k * NTHR1 + t);
      }
    }
    __syncthreads();
    int nc = min(sh[5], CCAP);
    if (sh[5] <= CCAP) {
      // exact rank by counting (keys unique: idx is in low bits)
      for (int c = t; c < nc; c += NTHR1) {
        u64 key = cand[c];
        int r = 0;
        for (int j = 0; j < nc; j++) r += (cand[j] < key);
        if (r < REM) {
          int ix = (int)(key & 0xFFFFFFFFu);
          gsorted[r] = enc_finite((u32)(key >> 32)) ? ix : (ix | (int)0x80000000);
        }
      }
    } else {
      // pathological-ties fallback: iterative extraction (never triggers on bench data)
      u32 gext = 0;
      for (int j = 0; j < T; j++) {
        u64 best = ~0ull;
#pragma unroll
        for (int k = 0; k < KPER; k++) {
          if (((cbits >> k) & 1u) && !((gext >> k) & 1u)) {
            u64 key = ((u64)dk[k] << 32) | (u32)(k * NTHR1 + t);
            if (key < best) best = key;
          }
        }
        u64 w = block_min_u64(best, red16, t);
        if (w == ~0ull) break;
        int idx = (int)(w & 0xFFFFFFFFu);
        if ((idx & (NTHR1 - 1)) == t) gext |= 1u << (idx >> 10);
        if (t == 0) gsorted[j] = enc_finite((u32)(w >> 32)) ? idx : (idx | (int)0x80000000);
      }
    }
    __syncthreads();
  }

  // ---- emit out_idx / out_valid / out_bucket / supernode_xyz ----
  {
    int slot = t;
    int idx, bucket;
    if (slot < 16) {
      idx = head_i[slot];
      bucket = head_bk[slot];
    } else {
      int jj = slot - 16;
      bool mk = (jj < nm) || (jj < 8 && ((extra_used >> jj) & 1u));
      if (mk) { idx = mpick[jj]; bucket = 2; }
      else {
        int g = gsorted[jj];
        if (rhv && g >= 0) { idx = g; bucket = 0; }
        else { idx = first_valid; bucket = -1; }
      }
    }
    bool ov = rhv && is_valid_el(validp, vmode, (long long)b * NPTS + idx);
    int ob = ov ? bucket : -1;
    size_t o = (size_t)b * M_SN + slot;
    out[O3 + o] = (float)idx;
    out[O4 + o] = ov ? 1.0f : 0.0f;
    out[O5 + o] = (float)ob;
    out[O1 + 3 * o + 0] = xyzb[3 * idx + 0];
    out[O1 + 3 * o + 1] = xyzb[3 * idx + 1];
    out[O1 + 3 * o + 2] = xyzb[3 * idx + 2];
  }
}

// ---------------- K2: KNN-16 + feature gather ----------------
// 8 supernodes per block of 256 threads; supernode = CONTIGUOUS 32-lane group
// (sl = t>>5) so stage reads are conflict-free and the merge is a 32-wide
// shuffle min-extraction (no LDS, no divergent rank scans).
// Hot loop: fp32 threshold compare only; exact u64 (d2_bits<<32|idx) order
// enforced in the buffered insertion chain (accept set is a superset).
#define NTHR2 256
#define CH 1024
#define SPB 8      // supernodes per block
#define SLICES 32  // threads per supernode
#define BUFD 8     // per-lane buffer depth

__device__ __forceinline__ void flush_buf(u64* best, const u64* buf, int t, int& cnt, float& thr) {
  int n = cnt;
  for (int c = 0; c < n; c++) {
    u64 k2 = buf[c * NTHR2 + t];
    if (k2 < best[15]) {
#pragma unroll
      for (int q = 0; q < 16; q++) {
        bool lt = k2 < best[q];
        u64 mn = lt ? k2 : best[q];
        u64 mx = lt ? best[q] : k2;
        best[q] = mn; k2 = mx;
      }
    }
  }
  cnt = 0;
  thr = __uint_as_float((u32)(best[15] >> 32));  // NaN while unfilled -> accepts all
}

__global__ __launch_bounds__(256)
void knn_kernel(const float* __restrict__ x, const float* __restrict__ xyz,
                const void* __restrict__ validp, const int* __restrict__ flagp,
                float* __restrict__ out) {
  // blob: [0,2048) u64 = float4 st[CH]; [2048,4096) = per-lane buffers
  __shared__ __align__(16) u64 blob[4096];          // 32 KB
  __shared__ u64 wn[SPB * KNN];                     // winners per supernode

  float4* st = (float4*)blob;
  u64* buf = blob + 2048;

  const int b = blockIdx.x >> 7;
  const int grp = blockIdx.x & 127;
  const int t = threadIdx.x;
  const int sl = t >> 5;             // supernode within group (contiguous 32 lanes)
  const int slice = t & 31;          // 0..31
  const int m = grp * SPB + sl;
  const int vmode = flagp[0];
  const float* xyzb = xyz + (size_t)b * NPTS * 3;

  const int sidx = (int)out[O3 + (size_t)b * M_SN + m];
  const float ax = xyzb[3 * sidx + 0];
  const float ay = xyzb[3 * sidx + 1];
  const float az = xyzb[3 * sidx + 2];
  const float sa = __fadd_rn(__fadd_rn(__fmul_rn(ax, ax), __fmul_rn(ay, ay)), __fmul_rn(az, az));

  u64 best[16];
#pragma unroll
  for (int q = 0; q < 16; q++) best[q] = ~0ull;
  int cnt = 0;
  float thr = INFINITY;

  for (int c0 = 0; c0 < NPTS; c0 += CH) {
    // stage CH points as float4 {x,y,z,|b|^2 or inf}
    for (int p = t; p < CH; p += NTHR2) {
      float px = xyzb[3 * (c0 + p)], py = xyzb[3 * (c0 + p) + 1], pz = xyzb[3 * (c0 + p) + 2];
      bool v = is_valid_el(validp, vmode, (long long)b * NPTS + c0 + p);
      float sb = __fadd_rn(__fadd_rn(__fmul_rn(px, px), __fmul_rn(py, py)), __fmul_rn(pz, pz));
      st[p] = make_float4(px, py, pz, v ? sb : INFINITY);
    }
    __syncthreads();
#pragma unroll 2
    for (int j = 0; j < CH / SLICES; j++) {
      int p = slice + SLICES * j;
      float4 v = st[p];
      float dot = __fadd_rn(__fadd_rn(__fmul_rn(ax, v.x), __fmul_rn(ay, v.y)), __fmul_rn(az, v.z));
      float d2 = __fsub_rn(__fadd_rn(sa, v.w), __fmul_rn(2.0f, dot));
      d2 = fmaxf(d2, 0.0f);
      if (!(d2 > thr)) {                         // NaN/inf thr -> accept (superset of exact u64 order)
        buf[cnt * NTHR2 + t] = ((u64)__float_as_uint(d2) << 32) | (u32)(c0 + p);
        cnt++;
      }
      if (__any(cnt == BUFD)) flush_buf(best, buf, t, cnt, thr);
    }
    __syncthreads();
  }
  flush_buf(best, buf, t, cnt, thr);

  // merge: 16-round 32-lane shuffle min-extraction per supernode group.
  // Keys are unique except the ~0ull sentinel (identical value -> benign multi-write).
  {
    u64 cur = best[0];
#pragma unroll 1
    for (int r = 0; r < KNN; r++) {
      u64 mn = cur;
#pragma unroll
      for (int d = 1; d < 32; d <<= 1) {
        u32 lo = __shfl_xor((u32)(mn & 0xFFFFFFFFu), d, 32);
        u32 hi = __shfl_xor((u32)(mn >> 32), d, 32);
        u64 o = ((u64)hi << 32) | lo;
        if (o < mn) mn = o;
      }
      if (cur == mn) {
        wn[sl * KNN + r] = mn;
#pragma unroll
        for (int q = 0; q < 15; q++) best[q] = best[q + 1];
        best[15] = ~0ull;
        cur = best[0];
      }
    }
  }
  __syncthreads();

  // emit neighbor_mask + gather features (2 threads per (supernode,k) row)
  {
    int s2 = t >> 5;            // 0..7
    int k2 = (t >> 1) & 15;     // 0..15
    int half = t & 1;
    int mm = grp * SPB + s2;
    u64 key = wn[s2 * KNN + k2];
    int ni = (int)(key & 0xFFFFFFFFu);
    size_t o2 = ((size_t)b * M_SN + mm) * KNN + k2;
    if (half == 0) out[O2 + o2] = ((u32)(key >> 32) < 0x7F800000u) ? 1.0f : 0.0f;
    const float4* src = (const float4*)(x + ((size_t)b * NPTS + ni) * CCH);
    float4* dst = (float4*)(out + O0 + o2 * CCH);
#pragma unroll
    for (int q = 0; q < 8; q++) dst[half * 8 + q] = src[half * 8 + q];
  }
}

extern "C" void kernel_launch(void* const* d_in, const int* in_sizes, int n_in,
                              void* d_out, int out_size, void* d_ws, size_t ws_size,
                              hipStream_t stream) {
  const float* x = (const float*)d_in[0];
  const float* xyz = (const float*)d_in[1];
  const void* valid = d_in[2];
  const float* state = (const float*)d_in[3];
  const int* mask_id = (const int*)d_in[4];
  const float* extra = (const float*)d_in[5];
  const float* glob = (const float*)d_in[6];
  float* out = (float*)d_out;
  int* flag = (int*)d_ws;

  detect_valid<<<1, 1024, 0, stream>>>((const unsigned*)valid, in_sizes[2] / 4, flag);
  sample_kernel<<<BF, NTHR1, 0, stream>>>(xyz, valid, state, mask_id, extra, glob, flag, out);
  knn_kernel<<<BF * 128, NTHR2, 0, stream>>>(x, xyz, valid, flag, out);
}

// Round 4
// 369.207 us; speedup vs baseline: 4.1334x; 1.4919x over previous
//
#include <hip/hip_runtime.h>
#include <math.h>

typedef unsigned long long u64;
typedef unsigned int u32;

#define BF 8
#define NPTS 16384
#define M_SN 1024
#define CCH 64
#define KNN 16
#define NTHR1 1024
#define KPER 16            // NPTS / NTHR1
#define TBL 4096
#define CCAP 3072
#define REM 1008           // M - 16 gripper slots

// output layout (flat float32, concatenated in return order)
constexpr size_t O0 = 0;                 // neighbor_feats 8*1024*16*64
constexpr size_t O1 = 8388608;           // supernode_xyz 8*1024*3
constexpr size_t O2 = 8413184;           // neighbor_mask 8*1024*16
constexpr size_t O3 = 8544256;           // out_idx 8*1024
constexpr size_t O4 = 8552448;           // out_valid 8*1024
constexpr size_t O5 = 8560640;           // out_bucket 8*1024

__device__ __forceinline__ bool is_valid_el(const void* vp, int mode, long long i) {
  if (mode == 1) return ((const unsigned char*)vp)[i] != 0;
  if (mode == 2) return ((const float*)vp)[i] != 0.0f;
  return ((const int*)vp)[i] != 0;
}

// monotone-decreasing encode: larger float -> smaller u32 (NaN sorts first; -inf last)
__device__ __forceinline__ u32 desc_enc(float f) {
  u32 u = __float_as_uint(f);
  u32 s = (u & 0x80000000u) ? ~u : (u | 0x80000000u);
  return ~s;
}
__device__ __forceinline__ bool enc_finite(u32 d) {
  u32 s = ~d;
  u32 u = (s & 0x80000000u) ? (s & 0x7FFFFFFFu) : ~s;
  return (u & 0x7F800000u) != 0x7F800000u;
}

__device__ __forceinline__ u64 wave_min_u64(u64 v) {
#pragma unroll
  for (int d = 32; d >= 1; d >>= 1) {
    u32 lo = __shfl_xor((u32)(v & 0xFFFFFFFFu), d, 64);
    u32 hi = __shfl_xor((u32)(v >> 32), d, 64);
    u64 o = ((u64)hi << 32) | lo;
    if (o < v) v = o;
  }
  return v;
}

// block-wide min over 1024 threads; red16 is a dedicated u64[16] LDS array
__device__ __forceinline__ u64 block_min_u64(u64 v, u64* red16, int t) {
  v = wave_min_u64(v);
  if ((t & 63) == 0) red16[t >> 6] = v;
  __syncthreads();
  if (t < 64) {
    u64 x = red16[t & 15];
    x = wave_min_u64(x);
    if (t == 0) red16[0] = x;
  }
  __syncthreads();
  u64 r = red16[0];
  __syncthreads();
  return r;
}

// exclusive prefix-sum of val across 1024 threads (2 barriers + trailing reuse barrier)
__device__ __forceinline__ int block_excl_scan(int val, int* scanb, int t, int* tot) {
  int incl = val;
#pragma unroll
  for (int d = 1; d < 64; d <<= 1) {
    int v = __shfl_up(incl, d, 64);
    if ((t & 63) >= d) incl += v;
  }
  if ((t & 63) == 63) scanb[t >> 6] = incl;
  __syncthreads();
  if (t < 64) {
    int ws = (t < 16) ? scanb[t] : 0;
#pragma unroll
    for (int d = 1; d < 16; d <<= 1) {
      int v = __shfl_up(ws, d, 64);
      if ((t & 63) >= d) ws += v;
    }
    if (t < 16) scanb[16 + t] = ws;
  }
  __syncthreads();
  int wv = t >> 6;
  int base = (wv == 0) ? 0 : scanb[16 + wv - 1];
  *tot = scanb[16 + 15];
  int r = base + incl - val;
  __syncthreads();   // scanb reusable after return
  return r;
}

// ---------------- K0: detect how `valid` (bool) is stored ----------------
__global__ void detect_valid(const unsigned* __restrict__ w, int nwords, int* __restrict__ flag) {
  __shared__ int cls;
  int t = threadIdx.x;
  if (t == 0) cls = 0;
  __syncthreads();
  int local = 0;
  for (int i = t; i < nwords; i += blockDim.x) {
    unsigned v = w[i];
    if (v == 0x3F800000u) local = 2;            // float32 storage
    else if (v != 0u && v != 1u) local = max(local, 1); // packed bytes
  }
  if (local) atomicMax(&cls, local);
  __syncthreads();
  if (t == 0) flag[0] = cls;                    // 0=int32, 1=uint8, 2=float32
}

// ---------------- K1: supernode sampling (one block per batch row) ----------------
__global__ __launch_bounds__(1024)
void sample_kernel(const float* __restrict__ xyz, const void* __restrict__ validp,
                   const float* __restrict__ state, const int* __restrict__ mask_id,
                   const float* __restrict__ extra, const float* __restrict__ glob,
                   const int* __restrict__ flagp, float* __restrict__ out) {
  __shared__ u64 red16[16];
  __shared__ int table[TBL];        // 16 KB (mask min-index table, reused as histogram)
  __shared__ int scanb[32];
  __shared__ int mpick[REM];        // ~4 KB
  __shared__ u64 cand[CCAP];        // 24 KB
  __shared__ int gsorted[REM];      // ~4 KB
  __shared__ int head_i[16];
  __shared__ int head_bk[16];
  __shared__ int sh[8];             // 0:rhv 1:first_valid 2:has_radius 4:n_avail 5:cand_cnt 6:B

  const int b = blockIdx.x, t = threadIdx.x;
  const int vmode = flagp[0];
  const float* xyzb = xyz + (size_t)b * NPTS * 3;
  const int* midb = mask_id + (size_t)b * NPTS;
  const float* exb = extra + (size_t)b * NPTS;
  const float* glb = glob + (size_t)b * NPTS;

  if (t < 8) sh[t] = 0;
  if (t == 1) sh[1] = 0x7FFFFFFF;
  if (t == 6) sh[6] = 0x7FFFFFFF;
  __syncthreads();

  // ---- validity bits (element i = k*1024 + t) ----
  u32 vbits = 0;
#pragma unroll
  for (int k = 0; k < KPER; k++) {
    int i = k * NTHR1 + t;
    if (is_valid_el(validp, vmode, (long long)b * NPTS + i)) vbits |= 1u << k;
  }
  if (vbits) {
    atomicOr(&sh[0], 1);
    atomicMin(&sh[1], (__ffs(vbits) - 1) * NTHR1 + t);
  }

  // ---- gripper distances ----
  float gx = state[b * 8 + 0], gy = state[b * 8 + 1], gz = state[b * 8 + 2];
  float gd[KPER];
  u32 inr = 0;
#pragma unroll
  for (int k = 0; k < KPER; k++) {
    int i = k * NTHR1 + t;
    float dx = xyzb[3 * i] - gx, dy = xyzb[3 * i + 1] - gy, dz = xyzb[3 * i + 2] - gz;
    float d = sqrtf((dx * dx + dy * dy) + dz * dz);
    gd[k] = d;
    if (((vbits >> k) & 1u) && d <= 0.1f) inr |= 1u << k;
  }
  if (inr) atomicOr(&sh[2], 1);
  __syncthreads();

  const int rhv = sh[0];
  const int first_valid = rhv ? sh[1] : 0;
  const u32 elig = vbits & (sh[2] ? inr : 0xFFFFu);
  u32 sel = 0;

  // ---- 16 gripper picks: iterative argmin of (gdist, idx) over eligible ----
  for (int it = 0; it < 16; ++it) {
    u64 best = ~0ull;
#pragma unroll
    for (int k = 0; k < KPER; k++) {
      if (((elig >> k) & 1u) && !((sel >> k) & 1u)) {
        u64 key = ((u64)__float_as_uint(gd[k]) << 32) | (u32)(k * NTHR1 + t);
        if (key < best) best = key;
      }
    }
    u64 w = block_min_u64(best, red16, t);
    bool keep = (w >> 32) < 0x7F800000ull;   // finite distance found
    int idx = (int)(w & 0xFFFFFFFFu);
    if (t == 0) { head_i[it] = keep ? idx : first_valid; head_bk[it] = keep ? 1 : -1; }
    if (keep && (idx & (NTHR1 - 1)) == t) sel |= 1u << (idx >> 10);
  }

  // ---- mask stage: min index per distinct mask_id among candidates ----
  for (int j = t; j < TBL; j += NTHR1) table[j] = 0x7FFFFFFF;
  __syncthreads();
#pragma unroll
  for (int k = 0; k < KPER; k++) {
    if (((vbits >> k) & 1u) && !((sel >> k) & 1u)) {
      int i = k * NTHR1 + t;
      int id = midb[i];
      if ((u32)id < TBL) atomicMin(&table[id], i);
    }
  }
  __syncthreads();
  int cnt = 0;
#pragma unroll
  for (int q = 0; q < 4; q++) cnt += (table[4 * t + q] != 0x7FFFFFFF);
  int mtot;
  int excl = block_excl_scan(cnt, scanb, t, &mtot);
  {
    int pos = excl;
#pragma unroll
    for (int q = 0; q < 4; q++) {
      int v = table[4 * t + q];
      if (v != 0x7FFFFFFF) { if (pos < REM) mpick[pos] = v; pos++; }
    }
  }
  __syncthreads();
  const int nm = min(mtot, REM);
  for (int j = 0; j < nm; j++) {
    int p = mpick[j];
    if ((p & (NTHR1 - 1)) == t) sel |= 1u << (p >> 10);
  }

  // ---- extra stage (only active when < 8 distinct mask ids) ----
  u32 extra_used = 0;
  if (nm < 8 && rhv) {
    u32 extrbits = 0;
    for (int j = 0; j < 8; j++) {
      u64 best = ~0ull;
#pragma unroll
      for (int k = 0; k < KPER; k++) {
        if (((vbits >> k) & 1u) && !((sel >> k) & 1u) && !((extrbits >> k) & 1u)) {
          int i = k * NTHR1 + t;
          u64 key = ((u64)desc_enc(exb[i]) << 32) | (u32)i;
          if (key < best) best = key;
        }
      }
      u64 w = block_min_u64(best, red16, t);
      if (w == ~0ull) break;                  // uniform: no candidates left
      int idx = (int)(w & 0xFFFFFFFFu);
      bool fin = enc_finite((u32)(w >> 32));
      if ((idx & (NTHR1 - 1)) == t) extrbits |= 1u << (idx >> 10);
      if (j >= nm && fin) {
        extra_used |= 1u << j;
        if (t == 0) mpick[j] = idx;
        if ((idx & (NTHR1 - 1)) == t) sel |= 1u << (idx >> 10);
      }
    }
    __syncthreads();
  }

  // ---- global stage: exact ordered top-1008 of (global_score desc, idx asc) ----
  for (int j = t; j < TBL; j += NTHR1) table[j] = 0;
  for (int j = t; j < REM; j += NTHR1) gsorted[j] = -1;
  __syncthreads();
  u32 cbits = vbits & ~sel;
  atomicAdd(&sh[4], __popc(cbits));
  u32 dk[KPER];
#pragma unroll
  for (int k = 0; k < KPER; k++) {
    if ((cbits >> k) & 1u) {
      dk[k] = desc_enc(glb[k * NTHR1 + t]);
      atomicAdd(&table[dk[k] >> 20], 1);
    }
  }
  __syncthreads();
  const int nav = sh[4];
  const int T = min(REM, nav);
  if (T > 0) {
    int c4 = table[4 * t] + table[4 * t + 1] + table[4 * t + 2] + table[4 * t + 3];
    int htot;
    int cum = block_excl_scan(c4, scanb, t, &htot);
#pragma unroll
    for (int q = 0; q < 4; q++) {
      int prev = cum;
      cum += table[4 * t + q];
      if (prev < T && cum >= T) atomicMin(&sh[6], 4 * t + q);
    }
    __syncthreads();
    const int B = sh[6];
#pragma unroll
    for (int k = 0; k < KPER; k++) {
      if (((cbits >> k) & 1u) && (int)(dk[k] >> 20) <= B) {
        int pos = atomicAdd(&sh[5], 1);
        if (pos < CCAP) cand[pos] = ((u64)dk[k] << 32) | (u32)(k * NTHR1 + t);
      }
    }
    __syncthreads();
    int nc = min(sh[5], CCAP);
    if (sh[5] <= CCAP) {
      // exact rank by counting (keys unique: idx is in low bits)
      for (int c = t; c < nc; c += NTHR1) {
        u64 key = cand[c];
        int r = 0;
        for (int j = 0; j < nc; j++) r += (cand[j] < key);
        if (r < REM) {
          int ix = (int)(key & 0xFFFFFFFFu);
          gsorted[r] = enc_finite((u32)(key >> 32)) ? ix : (ix | (int)0x80000000);
        }
      }
    } else {
      // pathological-ties fallback: iterative extraction (never triggers on bench data)
      u32 gext = 0;
      for (int j = 0; j < T; j++) {
        u64 best = ~0ull;
#pragma unroll
        for (int k = 0; k < KPER; k++) {
          if (((cbits >> k) & 1u) && !((gext >> k) & 1u)) {
            u64 key = ((u64)dk[k] << 32) | (u32)(k * NTHR1 + t);
            if (key < best) best = key;
          }
        }
        u64 w = block_min_u64(best, red16, t);
        if (w == ~0ull) break;
        int idx = (int)(w & 0xFFFFFFFFu);
        if ((idx & (NTHR1 - 1)) == t) gext |= 1u << (idx >> 10);
        if (t == 0) gsorted[j] = enc_finite((u32)(w >> 32)) ? idx : (idx | (int)0x80000000);
      }
    }
    __syncthreads();
  }

  // ---- emit out_idx / out_valid / out_bucket / supernode_xyz ----
  {
    int slot = t;
    int idx, bucket;
    if (slot < 16) {
      idx = head_i[slot];
      bucket = head_bk[slot];
    } else {
      int jj = slot - 16;
      bool mk = (jj < nm) || (jj < 8 && ((extra_used >> jj) & 1u));
      if (mk) { idx = mpick[jj]; bucket = 2; }
      else {
        int g = gsorted[jj];
        if (rhv && g >= 0) { idx = g; bucket = 0; }
        else { idx = first_valid; bucket = -1; }
      }
    }
    bool ov = rhv && is_valid_el(validp, vmode, (long long)b * NPTS + idx);
    int ob = ov ? bucket : -1;
    size_t o = (size_t)b * M_SN + slot;
    out[O3 + o] = (float)idx;
    out[O4 + o] = ov ? 1.0f : 0.0f;
    out[O5 + o] = (float)ob;
    out[O1 + 3 * o + 0] = xyzb[3 * idx + 0];
    out[O1 + 3 * o + 1] = xyzb[3 * idx + 1];
    out[O1 + 3 * o + 2] = xyzb[3 * idx + 2];
  }
}

// ---------------- K2: KNN-16 + feature gather ----------------
// 8 supernodes per block of 256 threads; supernode = contiguous 32-lane group.
// Group-shared distributed sorted top-16: lane l of the group holds the l-th
// smallest u64 key (d2_bits<<32|idx); threshold kth = true group 16th-best.
// Accepts (~127 per group over 16384 points) handled immediately via ballot +
// shuffle-broadcast + 8-instr distributed shift-insert. No per-lane heaps,
// no buffers, no end-merge.
#define NTHR2 256
#define CH 2048
#define SPB 8      // supernodes per block

__device__ __forceinline__ u64 shfl64_abs(u64 v, int src) {   // width-64 absolute lane
  u32 lo = (u32)__shfl((int)(u32)(v & 0xFFFFFFFFu), src, 64);
  u32 hi = (u32)__shfl((int)(u32)(v >> 32), src, 64);
  return ((u64)hi << 32) | lo;
}
__device__ __forceinline__ u64 shfl64_grp(u64 v, int src) {   // width-32 partitioned
  u32 lo = (u32)__shfl((int)(u32)(v & 0xFFFFFFFFu), src, 32);
  u32 hi = (u32)__shfl((int)(u32)(v >> 32), src, 32);
  return ((u64)hi << 32) | lo;
}
__device__ __forceinline__ u64 shflup64_grp(u64 v) {          // delta 1, width 32
  u32 lo = (u32)__shfl_up((int)(u32)(v & 0xFFFFFFFFu), 1, 32);
  u32 hi = (u32)__shfl_up((int)(u32)(v >> 32), 1, 32);
  return ((u64)hi << 32) | lo;
}

__global__ __launch_bounds__(256)
void knn_kernel(const float* __restrict__ x, const float* __restrict__ xyz,
                const void* __restrict__ validp, const int* __restrict__ flagp,
                float* __restrict__ out) {
  __shared__ __align__(16) float4 st[CH];           // 32 KB
  __shared__ u64 wn[SPB * KNN];                     // winners per supernode

  const int b = blockIdx.x >> 7;
  const int grp = blockIdx.x & 127;
  const int t = threadIdx.x;
  const int sl = t >> 5;             // supernode within block (contiguous 32 lanes)
  const int sub = t & 31;            // sublane within group
  const int lanebase = t & 32;       // 0 for lower wave half, 32 for upper
  const int m = grp * SPB + sl;
  const int vmode = flagp[0];
  const float* xyzb = xyz + (size_t)b * NPTS * 3;

  const int sidx = (int)out[O3 + (size_t)b * M_SN + m];
  const float ax = xyzb[3 * sidx + 0];
  const float ay = xyzb[3 * sidx + 1];
  const float az = xyzb[3 * sidx + 2];
  const float sa = __fadd_rn(__fadd_rn(__fmul_rn(ax, ax), __fmul_rn(ay, ay)), __fmul_rn(az, az));

  u64 lst = ~0ull;   // distributed sorted list element (lane sub = sub-th smallest)
  u64 kth = ~0ull;   // group 16th-best (replicated register)

  for (int c0 = 0; c0 < NPTS; c0 += CH) {
    // stage CH points as float4 {x,y,z,|b|^2 or inf}
    for (int p = t; p < CH; p += NTHR2) {
      float px = xyzb[3 * (c0 + p)], py = xyzb[3 * (c0 + p) + 1], pz = xyzb[3 * (c0 + p) + 2];
      bool v = is_valid_el(validp, vmode, (long long)b * NPTS + c0 + p);
      float sb = __fadd_rn(__fadd_rn(__fmul_rn(px, px), __fmul_rn(py, py)), __fmul_rn(pz, pz));
      st[p] = make_float4(px, py, pz, v ? sb : INFINITY);
    }
    __syncthreads();
#pragma unroll 4
    for (int j = 0; j < CH / 32; j++) {
      int p = sub + 32 * j;
      float4 v = st[p];
      float dot = __fadd_rn(__fadd_rn(__fmul_rn(ax, v.x), __fmul_rn(ay, v.y)), __fmul_rn(az, v.z));
      float d2 = __fsub_rn(__fadd_rn(sa, v.w), __fmul_rn(2.0f, dot));
      d2 = fmaxf(d2, 0.0f);
      u64 key = ((u64)__float_as_uint(d2) << 32) | (u32)(c0 + p);
      u64 bal = __ballot(key < kth);
      u32 mq = (u32)(bal >> lanebase);        // this group's accept queue
      while (mq) {
        int bb = __ffs(mq) - 1;
        mq &= mq - 1;
        u64 k = shfl64_abs(key, lanebase + bb);
        if (k < kth) {                        // group-uniform re-check (kth tightened)
          bool gt = lst > k;
          u64 shv = shflup64_grp(lst);
          int pg = __shfl_up(gt ? 1 : 0, 1, 32);
          if (sub == 0) pg = 0;
          lst = gt ? (pg ? shv : k) : lst;
          kth = shfl64_grp(lst, 15);
        }
      }
    }
    __syncthreads();
  }

  if (sub < KNN) wn[sl * KNN + sub] = lst;    // lane l = l-th nearest, exact order
  __syncthreads();

  // emit neighbor_mask + gather features (2 threads per (supernode,k) row)
  {
    int s2 = t >> 5;            // 0..7
    int k2 = (t >> 1) & 15;     // 0..15
    int half = t & 1;
    int mm = grp * SPB + s2;
    u64 key = wn[s2 * KNN + k2];
    int ni = (int)(key & 0xFFFFFFFFu);
    size_t o2 = ((size_t)b * M_SN + mm) * KNN + k2;
    if (half == 0) out[O2 + o2] = ((u32)(key >> 32) < 0x7F800000u) ? 1.0f : 0.0f;
    const float4* src = (const float4*)(x + ((size_t)b * NPTS + ni) * CCH);
    float4* dst = (float4*)(out + O0 + o2 * CCH);
#pragma unroll
    for (int q = 0; q < 8; q++) dst[half * 8 + q] = src[half * 8 + q];
  }
}

extern "C" void kernel_launch(void* const* d_in, const int* in_sizes, int n_in,
                              void* d_out, int out_size, void* d_ws, size_t ws_size,
                              hipStream_t stream) {
  const float* x = (const float*)d_in[0];
  const float* xyz = (const float*)d_in[1];
  const void* valid = d_in[2];
  const float* state = (const float*)d_in[3];
  const int* mask_id = (const int*)d_in[4];
  const float* extra = (const float*)d_in[5];
  const float* glob = (const float*)d_in[6];
  float* out = (float*)d_out;
  int* flag = (int*)d_ws;

  detect_valid<<<1, 1024, 0, stream>>>((const unsigned*)valid, in_sizes[2] / 4, flag);
  sample_kernel<<<BF, NTHR1, 0, stream>>>(xyz, valid, state, mask_id, extra, glob, flag, out);
  knn_kernel<<<BF * 128, NTHR2, 0, stream>>>(x, xyz, valid, flag, out);
}